// Round 1
// 113.912 us; speedup vs baseline: 1.0618x; 1.0618x over previous
//
#include <hip/hip_runtime.h>
#include <stdint.h>

typedef __bf16 bf16_t;
typedef __bf16 bf16x8 __attribute__((ext_vector_type(8)));
typedef float floatx4 __attribute__((ext_vector_type(4)));
typedef float floatx16 __attribute__((ext_vector_type(16)));

#define B_ 8
#define N_ 2048
#define D_ 768
#define H_ 64

// raw s_waitcnt imms (gfx9): vm[3:0]=bits3:0, lgkm=bits11:8
#define WAIT_VM0()   { __builtin_amdgcn_sched_barrier(0); __builtin_amdgcn_s_waitcnt(0x0F70); __builtin_amdgcn_sched_barrier(0); }
#define WAIT_LGKM0() { __builtin_amdgcn_sched_barrier(0); __builtin_amdgcn_s_waitcnt(0xC07F); __builtin_amdgcn_sched_barrier(0); }

// Native RNE cast: compiler emits v_cvt_pk_bf16_f32 (m240: beats bit-twiddle).
__device__ __forceinline__ bf16_t f2bf(float f) {
    return (bf16_t)f;
}

__device__ __forceinline__ uint32_t pkbf(float lo, float hi_) {
    union { bf16_t b[2]; uint32_t u; } t;
    t.b[0] = (bf16_t)lo; t.b[1] = (bf16_t)hi_;
    return t.u;
}

__device__ __forceinline__ void async_cp16(void* l, const void* g) {
    __builtin_amdgcn_global_load_lds(
        (const __attribute__((address_space(1))) uint32_t*)g,
        (__attribute__((address_space(3))) uint32_t*)l, 16, 0, 0);
}

// ---------------------------------------------------------------------------
// Kernel 1: W transpose + cast (unchanged except native cast).
// ---------------------------------------------------------------------------
__global__ void wt_kernel(const float* __restrict__ Wq,
                          const float* __restrict__ Wk,
                          const float* __restrict__ Wv,
                          bf16_t* __restrict__ Wt) {
    const int h = threadIdx.x;
    const int k = blockIdx.x;
    const int s = blockIdx.y;
    const float* W = (s == 0) ? Wq : (s == 1) ? Wk : Wv;
    float v = W[k * H_ + h];
    if (s == 0) v *= 0.125f * 1.4426950408889634f;
    Wt[(size_t)(s * 64 + h) * D_ + k] = f2bf(v);
}

// ---------------------------------------------------------------------------
// Kernel 2 (R10): fused QKV projection, full-width blocks.
// 512 blocks x 512 threads: each block owns one 32-row M-tile and ALL 192
// output cols (8 waves = 2 row-halves x 4 col-quarters of 48).  This halves
// the X HBM read vs the R9 N-split (each X row fetched ONCE).  LDS 64KB ->
// 2 blocks/CU x 8 waves = 16 waves/CU, same occupancy as R9's 4x4-wave
// config, so barrier-drain overlap across blocks is preserved.
// ---------------------------------------------------------------------------
__launch_bounds__(512, 4)
__global__ void proj_kernel(const float* __restrict__ X,
                            const bf16_t* __restrict__ Wt,
                            bf16_t* __restrict__ Qb,
                            bf16_t* __restrict__ Kb,
                            bf16_t* __restrict__ Vt) {
    const int wave = threadIdx.x >> 6;              // 0..7
    const int lane = threadIdx.x & 63;
    const int quad = lane >> 4;
    const int l16  = lane & 15;
    const int rowhalf = wave >> 2;                  // 0/1 -> 16-row half
    const int colq    = wave & 3;                   // 0..3 -> 48-col quarter
    const int m0blk = blockIdx.x * 32;

    __shared__ __align__(16) float  As[2][32 * 64];    // 16 KB
    __shared__ __align__(16) bf16_t Bs[2][192 * 64];   // 48 KB

    floatx4 acc[3];
#pragma unroll
    for (int i = 0; i < 3; i++) acc[i] = (floatx4){0.f, 0.f, 0.f, 0.f};

    auto stage = [&](int buf, int k0) {
        {
            const int r = wave * 4 + (lane >> 4);          // 0..31
            const int c = (lane & 15) ^ (r & 15);
            const float* g = X + (size_t)(m0blk + r) * D_ + k0 + c * 4;
            async_cp16((char*)&As[buf][0] + wave * 1024, g);
        }
#pragma unroll
        for (int i = 0; i < 3; i++) {
            const int r = (wave * 3 + i) * 8 + (lane >> 3); // 0..191
            const int c = (lane & 7) ^ (r & 7);
            const bf16_t* g = Wt + (size_t)r * D_ + k0 + c * 8;
            async_cp16((char*)&Bs[buf][0] + (wave * 3 + i) * 1024, g);
        }
    };

    const int arow = rowhalf * 16 + l16;

    stage(0, 0);
    for (int ch = 0; ch < 12; ch++) {
        __syncthreads();
        if (ch + 1 < 12) stage((ch + 1) & 1, (ch + 1) * 64);

        const char* Ab = (const char*)&As[ch & 1][0];
        const char* Bb = (const char*)&Bs[ch & 1][0];
#pragma unroll
        for (int kh = 0; kh < 2; kh++) {
            const int c0 = kh * 8 + quad * 2;
            float4 xa = *(const float4*)(Ab + arow * 256 + ((c0 ^ l16) & 15) * 16);
            float4 xb = *(const float4*)(Ab + arow * 256 + (((c0 + 1) ^ l16) & 15) * 16);
            bf16x8 af;
            af[0] = f2bf(xa.x); af[1] = f2bf(xa.y);
            af[2] = f2bf(xa.z); af[3] = f2bf(xa.w);
            af[4] = f2bf(xb.x); af[5] = f2bf(xb.y);
            af[6] = f2bf(xb.z); af[7] = f2bf(xb.w);
            const int cb = kh * 4 + quad;
#pragma unroll
            for (int nt = 0; nt < 3; nt++) {
                const int nl = colq * 48 + nt * 16 + l16;      // 0..191
                bf16x8 bf = *(const bf16x8*)(Bb + nl * 128 + ((cb ^ (nl & 7))) * 16);
                acc[nt] = __builtin_amdgcn_mfma_f32_16x16x32_bf16(af, bf, acc[nt], 0, 0, 0);
            }
        }
    }

#pragma unroll
    for (int nt = 0; nt < 3; nt++) {
        const int c = colq * 48 + nt * 16 + l16;               // 0..191
#pragma unroll
        for (int r = 0; r < 4; r++) {
            const int m = m0blk + rowhalf * 16 + quad * 4 + r;
            bf16_t val = f2bf(acc[nt][r]);
            if (c < 64) {
                Qb[(size_t)m * H_ + c] = val;
            } else if (c < 128) {
                Kb[(size_t)m * H_ + (c - 64)] = val;
            } else {
                const int b = m >> 11, n = m & 2047, h = c - 128;
                Vt[((size_t)b * H_ + h) * N_ + n] = val;
            }
        }
    }
}

// ---------------------------------------------------------------------------
// Kernel 3 (R10): flash attention, 32x32x16 MFMA, 512-thread blocks.
// Same structure as R9; P-pack path now uses native v_cvt_pk_bf16_f32 via
// plain casts (was ~80 VALU bit-twiddle instrs/iter), and the row-sum is a
// tree (depth 5) instead of a 16-deep serial add chain.
// ---------------------------------------------------------------------------
__launch_bounds__(512, 4)
__global__ void attn_kernel(const bf16_t* __restrict__ Qb,
                            const bf16_t* __restrict__ Kb,
                            const bf16_t* __restrict__ Vt,
                            float* __restrict__ Out) {
    const int x = blockIdx.x;            // 0..31
    const int b = blockIdx.y;            // 0..7
    const int z = blockIdx.z;            // 0..1
    const int qt = z ? (63 - x) : x;
    const int q0 = qt * 32;

    const int tid  = threadIdx.x;
    const int wave = tid >> 6;           // k-split 0..7
    const int lane = tid & 63;
    const int hi   = lane >> 5;
    const int lq   = lane & 31;

    // LDS: K staging 8 waves x 2 bufs x 4KB = 64KB; Ll 1KB after.
    // Ol[8][32][64] fp32 (64KB) aliases staging (used after __syncthreads).
    __shared__ __align__(16) char smem[8 * 8192 + 1024];
    char* mybase = smem + wave * 8192;
    float* Ol = (float*)smem;            // [8][32][64]
    float* Ll = (float*)(smem + 65536);  // [8][32]

    const bf16_t* KpB = Kb + (size_t)b * N_ * H_;
    const bf16_t* VpB = Vt + (size_t)b * H_ * N_;

    // Q B-frags: B[k=h][n=q], n=lq, k = s*16 + hi*8 + j
    const bf16_t* qrow = Qb + ((size_t)b * N_ + q0 + lq) * H_ + hi * 8;
    bf16x8 qf0 = *(const bf16x8*)(qrow);
    bf16x8 qf1 = *(const bf16x8*)(qrow + 16);
    bf16x8 qf2 = *(const bf16x8*)(qrow + 32);
    bf16x8 qf3 = *(const bf16x8*)(qrow + 48);

    floatx16 o0, o1;
#pragma unroll
    for (int i = 0; i < 16; i++) { o0[i] = 0.f; o1[i] = 0.f; }
    float ls = 0.f;

    // K DMA: 32 rows x 8 cells(16B); logical cell c at phys c^((r&7)^((r&8)>>1))
    const int rK = lane >> 3, cK = lane & 7;
    auto stage_k = [&](int k0, char* buf) {
#pragma unroll
        for (int i = 0; i < 4; i++) {
            const int r = i * 8 + rK;
            const int mk = rK ^ ((i & 1) << 2);
            async_cp16(buf + i * 1024,
                       KpB + (size_t)(k0 + r) * H_ + (cK ^ mk) * 8);
        }
    };

    const int ktm = qt;                  // inclusive max k-tile
    if (wave <= ktm)     stage_k(wave * 32, mybase);
    if (wave + 8 <= ktm) stage_k((wave + 8) * 32, mybase + 4096);

    const int mK = (lq & 7) ^ ((lq & 8) >> 1);

    for (int kt = wave; kt <= ktm; kt += 8) {
        const int k0 = kt * 32;
        char* kb = mybase + (((kt - wave) >> 3) & 1) * 4096;

        if (kt == wave) { WAIT_VM0(); }  // first iter: buffer fully landed

        // ---- K A-frags from staged LDS (conflict-free) ----
        bf16x8 kf0 = *(const bf16x8*)(kb + lq * 128 + (((0 + hi) ^ mK) * 16));
        bf16x8 kf1 = *(const bf16x8*)(kb + lq * 128 + (((2 + hi) ^ mK) * 16));
        bf16x8 kf2 = *(const bf16x8*)(kb + lq * 128 + (((4 + hi) ^ mK) * 16));
        bf16x8 kf3 = *(const bf16x8*)(kb + lq * 128 + (((6 + hi) ^ mK) * 16));
        WAIT_LGKM0();                    // reads done before buffer refill

        // ---- V direct loads (BEFORE refill DMA: compiler's V-wait then
        //      leaves the refill in flight while draining older DMAs) ----
        const bf16_t* vrow0 = VpB + (size_t)lq * N_ + k0 + 8 * hi;
        const bf16_t* vrow1 = vrow0 + (size_t)32 * N_;
        bf16x8 vf00 = *(const bf16x8*)(vrow0);        // t=0, s=0
        bf16x8 vf01 = *(const bf16x8*)(vrow0 + 16);   // t=0, s=1
        bf16x8 vf10 = *(const bf16x8*)(vrow1);        // t=1, s=0
        bf16x8 vf11 = *(const bf16x8*)(vrow1 + 16);   // t=1, s=1
        __builtin_amdgcn_sched_barrier(0);
        if (kt + 16 <= ktm) stage_k(k0 + 512, kb);

        // ---- S^T = K Q^T : [32 keys x 32 q] ----
        floatx16 st;
#pragma unroll
        for (int i = 0; i < 16; i++) st[i] = 0.f;
        st = __builtin_amdgcn_mfma_f32_32x32x16_bf16(kf0, qf0, st, 0, 0, 0);
        st = __builtin_amdgcn_mfma_f32_32x32x16_bf16(kf1, qf1, st, 0, 0, 0);
        st = __builtin_amdgcn_mfma_f32_32x32x16_bf16(kf2, qf2, st, 0, 0, 0);
        st = __builtin_amdgcn_mfma_f32_32x32x16_bf16(kf3, qf3, st, 0, 0, 0);

        // ---- mask (diag tile only) + exp2, in place ----
        if (kt < qt) {
#pragma unroll
            for (int r = 0; r < 16; r++) st[r] = exp2f(st[r]);
        } else {
#pragma unroll
            for (int r = 0; r < 16; r++) {
                const int row = (r & 3) + 8 * (r >> 2) + 4 * hi;   // key
                st[r] = (row <= lq) ? exp2f(st[r]) : 0.f;
            }
        }
        // tree row-sum (depth 5 instead of 16-deep serial chain)
        {
            float t0 = (st[0] + st[1]) + (st[2] + st[3]);
            float t1 = (st[4] + st[5]) + (st[6] + st[7]);
            float t2 = (st[8] + st[9]) + (st[10] + st[11]);
            float t3 = (st[12] + st[13]) + (st[14] + st[15]);
            ls += (t0 + t1) + (t2 + t3);
        }

        // ---- P C->A in registers: packed-pair exchange across hi halves.
        // pair t: (st[2t], st[2t+1]) = keys {2(t&1) + 8*(t>>1) + 4hi, +1}.
        uint32_t pb[8];
#pragma unroll
        for (int t = 0; t < 8; t++) pb[t] = pkbf(st[2 * t], st[2 * t + 1]);
        uint32_t rc[4];
#pragma unroll
        for (int t = 0; t < 4; t++) {
            const uint32_t w = hi ? pb[(t & 1) + 4 * (t >> 1)]
                                  : pb[(t & 1) + 2 + 4 * (t >> 1)];
            rc[t] = (uint32_t)__shfl_xor((int)w, 32, 64);
        }
        union { uint32_t u[4]; bf16x8 v; } f0, f1;
        f0.u[0] = hi ? rc[0] : pb[0]; f0.u[1] = hi ? rc[1] : pb[1];
        f0.u[2] = hi ? pb[2] : rc[0]; f0.u[3] = hi ? pb[3] : rc[1];
        f1.u[0] = hi ? rc[2] : pb[4]; f1.u[1] = hi ? rc[3] : pb[5];
        f1.u[2] = hi ? pb[6] : rc[2]; f1.u[3] = hi ? pb[7] : rc[3];

        // ---- PV ----
        o0 = __builtin_amdgcn_mfma_f32_32x32x16_bf16(f0.v, vf00, o0, 0, 0, 0);
        o0 = __builtin_amdgcn_mfma_f32_32x32x16_bf16(f1.v, vf01, o0, 0, 0, 0);
        o1 = __builtin_amdgcn_mfma_f32_32x32x16_bf16(f0.v, vf10, o1, 0, 0, 0);
        o1 = __builtin_amdgcn_mfma_f32_32x32x16_bf16(f1.v, vf11, o1, 0, 0, 0);
    }

    // ---- merge 8-way k-split: all waves dump partials, parallel reduce ----
    float lst = ls + __shfl_xor(ls, 32, 64);
    __syncthreads();                     // staging region dead from here
    if (hi == 0) Ll[wave * 32 + lq] = lst;
#pragma unroll
    for (int r = 0; r < 16; r++) {
        const int q = (r & 3) + 8 * (r >> 2) + 4 * hi;
        Ol[((size_t)wave * 32 + q) * 64 + lq]      = o0[r];
        Ol[((size_t)wave * 32 + q) * 64 + 32 + lq] = o1[r];
    }
    __syncthreads();
    {
        const int q  = tid >> 4;         // 0..31
        const int h4 = (tid & 15) * 4;   // 0..60
        floatx4 a = (floatx4){0.f, 0.f, 0.f, 0.f};
        float l = 0.f;
#pragma unroll
        for (int w = 0; w < 8; w++) {
            const floatx4 part = *(const floatx4*)&Ol[((size_t)w * 32 + q) * 64 + h4];
            a += part;
            l += Ll[w * 32 + q];
        }
        const float inv = 1.0f / l;
        float4 outv = {a[0] * inv, a[1] * inv, a[2] * inv, a[3] * inv};
        *(float4*)&Out[((size_t)b * N_ + q0 + q) * H_ + h4] = outv;
    }
}

// ---------------------------------------------------------------------------
extern "C" void kernel_launch(void* const* d_in, const int* in_sizes, int n_in,
                              void* d_out, int out_size, void* d_ws, size_t ws_size,
                              hipStream_t stream) {
    const float* X  = (const float*)d_in[0];
    const float* Wq = (const float*)d_in[1];
    const float* Wk = (const float*)d_in[2];
    const float* Wv = (const float*)d_in[3];
    float* Out = (float*)d_out;

    char* ws = (char*)d_ws;
    bf16_t* Qb = (bf16_t*)(ws);
    bf16_t* Kb = (bf16_t*)(ws + (size_t)(2u << 20));
    bf16_t* Vt = (bf16_t*)(ws + (size_t)(4u << 20));
    bf16_t* Wt = (bf16_t*)(ws + (size_t)(6u << 20));

    hipLaunchKernelGGL(wt_kernel, dim3(768, 3), dim3(64), 0, stream, Wq, Wk, Wv, Wt);
    hipLaunchKernelGGL(proj_kernel, dim3(512), dim3(512), 0, stream, X, Wt, Qb, Kb, Vt);
    hipLaunchKernelGGL(attn_kernel, dim3(32, 8, 2), dim3(512), 0, stream, Qb, Kb, Vt, Out);
}